// Round 1
// baseline (108254.382 us; speedup 1.0000x reference)
//
#include <hip/hip_runtime.h>

typedef unsigned short u16;
typedef __attribute__((ext_vector_type(4))) float f32x4;
typedef __attribute__((ext_vector_type(8))) short short8;

#define NUM_T 256
#define BATCH 1024
#define DIM 64
#define HID 768
#define PHID 512
#define PREP 10
#define GIN 640            // DIM*PREP
#define COVSZ 32
#define COVH 128
#define DT_ 0.05f
#define VEPS 1e-6f
#define NTH 512
#define NWG 64

// LDS row strides (elements); +8 bf16 pad => row stride ≡ 4 mod 32 banks (2-way, free)
#define LHF 772
#define LHB 776
#define LPH 520
#define LPF 132
#define LPB 136
#define LGI 648

struct Params {
  const float *X, *M; const int *obs; const float *cov;
  const float *bxz, *bxn, *bp1, *bp2, *bc1, *bc2, *bih, *bhh, *wprep, *bprep;
  const float *Wc1, *Wc2;
  const u16 *Wxz, *Wxn, *Whz, *Whn, *Wp1, *Wp2, *Wih, *Whh;
  float *out_h; float *partials;
};

__device__ __forceinline__ u16 f2bf(float f){
  unsigned u = __builtin_bit_cast(unsigned, f);
  u = (u + 0x7FFFu + ((u >> 16) & 1u)) >> 16;
  return (u16)u;
}
__device__ __forceinline__ float bf2f(u16 h){
  unsigned u = ((unsigned)h) << 16;
  return __builtin_bit_cast(float, u);
}
__device__ __forceinline__ float sigm(float x){ return 1.0f/(1.0f + __expf(-x)); }
__device__ __forceinline__ float tanh_f(float x){
  float t = __expf(-2.0f*fabsf(x));
  float r = (1.0f - t)/(1.0f + t);
  return x >= 0.0f ? r : -r;
}

struct Smem {
  float h_f[16*LHF];     // fp32 master h
  u16   h_b[16*LHB];     // bf16 copy (MFMA A operand)
  u16   ph1[16*LPH];
  float p_f[16*LPF];     // fp32 p for NLL
  u16   p_b[16*LPB];     // bf16 p for ODE GEMMs
  union U {
    struct ZN { u16 z_b[16*LHB]; u16 zh_b[16*LHB]; } zn;
    u16 gi_b[16*LGI];
  } u;
  int om[16];
  float red[8];
};

// NT output tiles (spaced 8 apart in n), shared A fragment. A: LDS [16][lda] bf16.
// W: global bf16 row-major [N][K]. c = lane&15, g = lane>>4.
template<int K, int NT>
__device__ __forceinline__ void dotK(const u16* __restrict__ A, int lda,
    const u16* __restrict__ W, f32x4* acc, int c, int g, int wave)
{
  const u16* a = A + c*lda + g*8;
  const u16* w[NT];
  #pragma unroll
  for (int j = 0; j < NT; ++j)
    w[j] = W + (size_t)(((wave + 8*j)*16) + c)*K + g*8;
  #pragma unroll
  for (int k0 = 0; k0 < K; k0 += 32){
    short8 av = *(const short8*)(a + k0);
    #pragma unroll
    for (int j = 0; j < NT; ++j){
      short8 bv = *(const short8*)(w[j] + k0);
      acc[j] = __builtin_amdgcn_mfma_f32_16x16x32_bf16(av, bv, acc[j], 0, 0, 0);
    }
  }
}

// 3 chunk-GEMMs (rows n, 768+n, 1536+n of W) sharing one A stream (for GRUCell).
template<int K>
__device__ __forceinline__ void dot3(const u16* __restrict__ A, int lda,
    const u16* __restrict__ W, int n, f32x4& a0, f32x4& a1, f32x4& a2, int c, int g)
{
  const u16* a  = A + c*lda + g*8;
  const u16* w0 = W + (size_t)(n)*K + g*8;
  const u16* w1 = W + (size_t)(HID + n)*K + g*8;
  const u16* w2 = W + (size_t)(2*HID + n)*K + g*8;
  #pragma unroll
  for (int k0 = 0; k0 < K; k0 += 32){
    short8 av = *(const short8*)(a + k0);
    a0 = __builtin_amdgcn_mfma_f32_16x16x32_bf16(av, *(const short8*)(w0 + k0), a0, 0,0,0);
    a1 = __builtin_amdgcn_mfma_f32_16x16x32_bf16(av, *(const short8*)(w1 + k0), a1, 0,0,0);
    a2 = __builtin_amdgcn_mfma_f32_16x16x32_bf16(av, *(const short8*)(w2 + k0), a2, 0,0,0);
  }
}

__global__ __launch_bounds__(NTH, 2) void nnfo_main(Params pr)
{
  __shared__ Smem sm;
  const int tid  = threadIdx.x;
  const int lane = tid & 63;
  const int wave = tid >> 6;
  const int c = lane & 15;    // A-row for loads, output col for results
  const int g = lane >> 4;    // k-group; output rows g*4+i
  const int wg = blockIdx.x;
  const int row0 = wg * 16;

  float loss = 0.0f;

  // ---- prologue: h0 = tanh(relu(cov@Wc1^T + bc1)@Wc2^T + bc2), fp32 scalar ----
  for (int it = tid; it < 16*COVH; it += NTH){
    int r = it >> 7, j = it & 127;
    float acc = pr.bc1[j];
    const float* cv = pr.cov + (size_t)(row0 + r)*COVSZ;
    const float* w  = pr.Wc1 + (size_t)j*COVSZ;
    for (int k = 0; k < COVSZ; ++k) acc += cv[k]*w[k];
    sm.p_f[r*LPF + j] = fmaxf(acc, 0.0f);
  }
  __syncthreads();
  for (int it = tid; it < 16*HID; it += NTH){
    int r = it / HID, j = it - r*HID;
    float acc = pr.bc2[j];
    const float* w = pr.Wc2 + (size_t)j*COVH;
    for (int k = 0; k < COVH; ++k) acc += sm.p_f[r*LPF + k]*w[k];
    float h = tanh_f(acc);
    sm.h_f[r*LHF + j] = h;
    sm.h_b[r*LHB + j] = f2bf(h);
  }
  __syncthreads();

  // p_model part 1: ph1 = relu(h@Wp1^T + bp1)   (N=512, NT=4)
  auto pm1 = [&]() {
    f32x4 acc[4] = {};
    dotK<HID, 4>(sm.h_b, LHB, pr.Wp1, acc, c, g, wave);
    #pragma unroll
    for (int j = 0; j < 4; ++j){
      int n = (wave + 8*j)*16 + c;
      float b = pr.bp1[n];
      #pragma unroll
      for (int i = 0; i < 4; ++i)
        sm.ph1[(g*4 + i)*LPH + n] = f2bf(fmaxf(acc[j][i] + b, 0.0f));
    }
  };
  // p_model part 2 -> fp32 p (for NLL)  (N=128, NT=1)
  auto pm2_f32 = [&]() {
    f32x4 acc[1] = {};
    dotK<PHID, 1>(sm.ph1, LPH, pr.Wp2, acc, c, g, wave);
    int n = wave*16 + c;
    float b = pr.bp2[n];
    #pragma unroll
    for (int i = 0; i < 4; ++i) sm.p_f[(g*4 + i)*LPF + n] = acc[0][i] + b;
  };
  // NLL accumulate (0.5*(err^2+log av)*Mm); optionally also build gi
  auto nll = [&](bool build_gi) {
    for (int it = tid; it < 16*DIM; it += NTH){
      int r = it >> 6, d = it & 63;
      size_t xoff = ((size_t)0)* 0 + (size_t)(row0 + r)*DIM + d; // filled per-t below
      (void)xoff;
    }
  };
  (void)nll;

  #pragma unroll 1
  for (int t = 0; t < NUM_T; ++t){
    if (tid < 16) sm.om[tid] = pr.obs[(size_t)t*BATCH + row0 + tid];

    // ---- stage 1: ph1 from current h ----
    pm1();
    __syncthreads();

    // ---- stage 2: ODE p -> bf16 ----
    {
      f32x4 acc[1] = {};
      dotK<PHID, 1>(sm.ph1, LPH, pr.Wp2, acc, c, g, wave);
      int n = wave*16 + c;
      float b = pr.bp2[n];
      #pragma unroll
      for (int i = 0; i < 4; ++i) sm.p_b[(g*4 + i)*LPB + n] = f2bf(acc[0][i] + b);
    }
    __syncthreads();

    // ---- stage 3: z = sigmoid(p@Wxz^T + bxz + h@Whz^T); store z, z*h ----
    {
      f32x4 acc[6] = {};
      dotK<128, 6>(sm.p_b, LPB, pr.Wxz, acc, c, g, wave);
      dotK<HID, 6>(sm.h_b, LHB, pr.Whz, acc, c, g, wave);
      #pragma unroll
      for (int j = 0; j < 6; ++j){
        int n = (wave + 8*j)*16 + c;
        float b = pr.bxz[n];
        #pragma unroll
        for (int i = 0; i < 4; ++i){
          int r = g*4 + i;
          float z = sigm(acc[j][i] + b);
          float h = sm.h_f[r*LHF + n];
          sm.u.zn.z_b [r*LHB + n] = f2bf(z);
          sm.u.zn.zh_b[r*LHB + n] = f2bf(z*h);
        }
      }
    }
    __syncthreads();

    // ---- stage 4: n = tanh(p@Wxn^T + bxn + (z*h)@Whn^T); h += dt*(1-z)*(n-h) ----
    {
      f32x4 acc[6] = {};
      dotK<128, 6>(sm.p_b, LPB, pr.Wxn, acc, c, g, wave);
      dotK<HID, 6>(sm.u.zn.zh_b, LHB, pr.Whn, acc, c, g, wave);
      #pragma unroll
      for (int j = 0; j < 6; ++j){
        int n = (wave + 8*j)*16 + c;
        float b = pr.bxn[n];
        #pragma unroll
        for (int i = 0; i < 4; ++i){
          int r = g*4 + i;
          float nv = tanh_f(acc[j][i] + b);
          float z  = bf2f(sm.u.zn.z_b[r*LHB + n]);
          float h  = sm.h_f[r*LHF + n];
          h = h + DT_*(1.0f - z)*(nv - h);
          sm.h_f[r*LHF + n] = h;
          sm.h_b[r*LHB + n] = f2bf(h);
        }
      }
    }
    __syncthreads();

    // ---- stages 5-6: p2 = p_model(h) -> fp32 ----
    pm1();
    __syncthreads();
    pm2_f32();
    __syncthreads();

    // ---- stage 7: nll_pre + build gi ----
    for (int it = tid; it < 16*DIM; it += NTH){
      int r = it >> 6, d = it & 63;
      size_t xoff = ((size_t)t*BATCH + row0 + r)*DIM + d;
      float Xv = pr.X[xoff];
      float om = sm.om[r] ? 1.0f : 0.0f;
      float Mv = pr.M[xoff] * om;
      float mean = sm.p_f[r*LPF + d];
      float var  = sm.p_f[r*LPF + 64 + d];
      float av   = fabsf(var) + VEPS;
      float inv  = rsqrtf(av);
      float errv = (Xv - mean)*inv;
      loss += 0.5f*(errv*errv + __logf(av))*Mv;
      #pragma unroll
      for (int p = 0; p < PREP; ++p){
        float s = pr.bprep[d*PREP + p]
                + Xv  * pr.wprep[(d*4 + 0)*PREP + p]
                + mean* pr.wprep[(d*4 + 1)*PREP + p]
                + av  * pr.wprep[(d*4 + 2)*PREP + p]
                + errv* pr.wprep[(d*4 + 3)*PREP + p];
        sm.u.gi_b[r*LGI + d*PREP + p] = f2bf(fmaxf(s, 0.0f)*Mv);
      }
    }
    __syncthreads();

    // ---- stage 8: GRUCell jump ----
    {
      float hn_buf[6][4];
      #pragma unroll
      for (int j = 0; j < 6; ++j){
        int n = (wave + 8*j)*16 + c;
        f32x4 ar = {}, az = {}, an = {};
        dot3<GIN>(sm.u.gi_b, LGI, pr.Wih, n, ar, az, an, c, g);
        f32x4 br = {}, bz = {}, bn = {};
        dot3<HID>(sm.h_b, LHB, pr.Whh, n, br, bz, bn, c, g);
        #pragma unroll
        for (int i = 0; i < 4; ++i){
          int r = g*4 + i;
          float ir = ar[i] + pr.bih[n];
          float iz = az[i] + pr.bih[HID + n];
          float in = an[i] + pr.bih[2*HID + n];
          float hr = br[i] + pr.bhh[n];
          float hz = bz[i] + pr.bhh[HID + n];
          float hn = bn[i] + pr.bhh[2*HID + n];
          float rr  = sigm(ir + hr);
          float zz  = sigm(iz + hz);
          float nn  = tanh_f(in + rr*hn);
          float ho  = sm.h_f[r*LHF + n];
          hn_buf[j][i] = (1.0f - zz)*nn + zz*ho;
        }
      }
      __syncthreads();   // all reads of h_b/h_f done before conditional overwrite
      #pragma unroll
      for (int j = 0; j < 6; ++j){
        int n = (wave + 8*j)*16 + c;
        #pragma unroll
        for (int i = 0; i < 4; ++i){
          int r = g*4 + i;
          if (sm.om[r]){
            float v = hn_buf[j][i];
            sm.h_f[r*LHF + n] = v;
            sm.h_b[r*LHB + n] = f2bf(v);
          }
        }
      }
    }
    __syncthreads();

    // ---- stages 9-10: p3 = p_model(h) -> fp32 ----
    pm1();
    __syncthreads();
    pm2_f32();
    __syncthreads();

    // ---- stage 11: nll_post ----
    for (int it = tid; it < 16*DIM; it += NTH){
      int r = it >> 6, d = it & 63;
      size_t xoff = ((size_t)t*BATCH + row0 + r)*DIM + d;
      float Xv = pr.X[xoff];
      float om = sm.om[r] ? 1.0f : 0.0f;
      float Mv = pr.M[xoff] * om;
      float mean = sm.p_f[r*LPF + d];
      float var  = sm.p_f[r*LPF + 64 + d];
      float av   = fabsf(var) + VEPS;
      float inv  = rsqrtf(av);
      float errv = (Xv - mean)*inv;
      loss += 0.5f*(errv*errv + __logf(av))*Mv;   // MIXING = 1
    }
    __syncthreads();
  }

  // ---- write h rows (fp32) ----
  for (int it = tid; it < 16*HID; it += NTH){
    int r = it / HID, j = it - r*HID;
    pr.out_h[(size_t)(row0 + r)*HID + j] = sm.h_f[r*LHF + j];
  }
  // ---- loss reduce: wave shuffle -> LDS -> per-WG partial ----
  #pragma unroll
  for (int off = 32; off >= 1; off >>= 1) loss += __shfl_down(loss, off);
  if (lane == 0) sm.red[wave] = loss;
  __syncthreads();
  if (tid == 0){
    float s = 0.0f;
    for (int w = 0; w < 8; ++w) s += sm.red[w];
    pr.partials[wg] = s;
  }
}

__global__ void k_convert(const float* __restrict__ s, u16* __restrict__ d, int n){
  int i = blockIdx.x*blockDim.x + threadIdx.x;
  if (i < n) d[i] = f2bf(s[i]);
}

__global__ void k_final(const float* __restrict__ partials, float* __restrict__ out_loss){
  float v = partials[threadIdx.x];
  #pragma unroll
  for (int off = 32; off >= 1; off >>= 1) v += __shfl_down(v, off);
  if (threadIdx.x == 0) out_loss[0] = v;
}

extern "C" void kernel_launch(void* const* d_in, const int* in_sizes, int n_in,
                              void* d_out, int out_size, void* d_ws, size_t ws_size,
                              hipStream_t stream)
{
  const float* X   = (const float*)d_in[0];
  const float* M   = (const float*)d_in[1];
  const int*   obs = (const int*)  d_in[2];
  const float* cov = (const float*)d_in[3];
  const float* Wxz = (const float*)d_in[4];
  const float* bxz = (const float*)d_in[5];
  const float* Wxn = (const float*)d_in[6];
  const float* bxn = (const float*)d_in[7];
  const float* Whz = (const float*)d_in[8];
  const float* Whn = (const float*)d_in[9];
  const float* Wp1 = (const float*)d_in[10];
  const float* bp1 = (const float*)d_in[11];
  const float* Wp2 = (const float*)d_in[12];
  const float* bp2 = (const float*)d_in[13];
  const float* Wc1 = (const float*)d_in[14];
  const float* bc1 = (const float*)d_in[15];
  const float* Wc2 = (const float*)d_in[16];
  const float* bc2 = (const float*)d_in[17];
  const float* Wih = (const float*)d_in[18];
  const float* Whh = (const float*)d_in[19];
  const float* bih = (const float*)d_in[20];
  const float* bhh = (const float*)d_in[21];
  const float* wprep = (const float*)d_in[22];
  const float* bprep = (const float*)d_in[23];

  u16* w = (u16*)d_ws;
  u16* wXZ = w + 0;         // 768*128
  u16* wXN = w + 98304;     // 768*128
  u16* wHZ = w + 196608;    // 768*768
  u16* wHN = w + 786432;    // 768*768
  u16* wP1 = w + 1376256;   // 512*768
  u16* wP2 = w + 1769472;   // 128*512
  u16* wIH = w + 1835008;   // 2304*640
  u16* wHH = w + 3309568;   // 2304*768
  float* partials = (float*)((char*)d_ws + 10158080);

  struct CV { const float* s; u16* d; int n; } cvs[8] = {
    {Wxz, wXZ,  98304}, {Wxn, wXN,  98304}, {Whz, wHZ, 589824}, {Whn, wHN, 589824},
    {Wp1, wP1, 393216}, {Wp2, wP2,  65536}, {Wih, wIH, 1474560}, {Whh, wHH, 1769472},
  };
  for (int i = 0; i < 8; ++i)
    k_convert<<<(cvs[i].n + 255)/256, 256, 0, stream>>>(cvs[i].s, cvs[i].d, cvs[i].n);

  Params pr { X, M, obs, cov, bxz, bxn, bp1, bp2, bc1, bc2, bih, bhh, wprep, bprep,
              Wc1, Wc2, wXZ, wXN, wHZ, wHN, wP1, wP2, wIH, wHH,
              (float*)d_out, partials };
  nnfo_main<<<NWG, NTH, 0, stream>>>(pr);
  k_final<<<1, 64, 0, stream>>>(partials, (float*)d_out + (size_t)BATCH*HID);
}